// Round 2
// baseline (154.213 us; speedup 1.0000x reference)
//
#include <hip/hip_runtime.h>

#define BATCH 100000

__device__ __forceinline__ float relu(float v) { return fmaxf(v, 0.f); }

__global__ __launch_bounds__(256, 4) void barrier_net(
    const float* __restrict__ x,
    const float* __restrict__ phi_w1, const float* __restrict__ phi_b1,
    const float* __restrict__ phi_w2, const float* __restrict__ phi_b2,
    const float* __restrict__ obs_w1, const float* __restrict__ obs_b1,
    const float* __restrict__ obs_w2, const float* __restrict__ obs_b2,
    const float* __restrict__ rho_w1, const float* __restrict__ rho_b1,
    const float* __restrict__ rho_w2, const float* __restrict__ rho_b2,
    const float* __restrict__ psi_w1, const float* __restrict__ psi_b1,
    const float* __restrict__ psi_w2, const float* __restrict__ psi_b2,
    float2* __restrict__ out)
{
    const int s = blockIdx.x * 256 + threadIdx.x;
    if (s >= BATCH) return;
    const float* xr = x + (size_t)s * 85;

    // ---- sample load: g + 16 neighbors (4 feat) ----
    float g0 = xr[0];
    float g1 = xr[1];
    float nb[16][4];
#pragma unroll
    for (int n = 0; n < 16; ++n)
#pragma unroll
        for (int k = 0; k < 4; ++k)
            nb[n][k] = xr[5 + n * 4 + k];

    // ---- barrier: sum_n (0.01/(|p|-0.2)) * p,  p = -nb[:,0:2] ----
    float bar0 = 0.f, bar1 = 0.f;
#pragma unroll
    for (int n = 0; n < 16; ++n) {
        float p0 = -nb[n][0], p1 = -nb[n][1];
        float r  = __builtin_amdgcn_sqrtf(fmaf(p0, p0, p1 * p1));
        float sc = 0.01f * __builtin_amdgcn_rcpf(r - 0.2f);
        bar0 = fmaf(sc, p0, bar0);
        bar1 = fmaf(sc, p1, bar1);
    }

    // ---- acc = NN*phi_b2 + NO*obs_b2 (second layers are linear: W2 after the sum) ----
    float acc[16];
#pragma unroll
    for (int j = 0; j < 16; ++j)
        acc[j] = fmaf(16.f, phi_b2[j], 8.f * obs_b2[j]);

    // ---- phi: acc += (sum_n relu(nb_n @ W1 + b1)) @ W2 ----
#pragma unroll 2
    for (int h = 0; h < 64; ++h) {
        float w0 = phi_w1[h], w1 = phi_w1[64 + h], w2 = phi_w1[128 + h], w3 = phi_w1[192 + h];
        float b  = phi_b1[h];
        float hs = 0.f;
#pragma unroll
        for (int n = 0; n < 16; ++n) {
            float t = fmaf(nb[n][0], w0, fmaf(nb[n][1], w1, fmaf(nb[n][2], w2, fmaf(nb[n][3], w3, b))));
            hs += relu(t);
        }
#pragma unroll
        for (int j = 0; j < 16; ++j)
            acc[j] = fmaf(hs, phi_w2[h * 16 + j], acc[j]);
    }

    // ---- obs: acc += (sum_o relu(ob_o @ W1 + b1)) @ W2 ----
    float obv[8][2];
#pragma unroll
    for (int o = 0; o < 8; ++o) {
        obv[o][0] = xr[69 + o * 2];
        obv[o][1] = xr[69 + o * 2 + 1];
    }
#pragma unroll 2
    for (int h = 0; h < 64; ++h) {
        float w0 = obs_w1[h], w1 = obs_w1[64 + h];
        float b  = obs_b1[h];
        float hs = 0.f;
#pragma unroll
        for (int o = 0; o < 8; ++o)
            hs += relu(fmaf(obv[o][0], w0, fmaf(obv[o][1], w1, b)));
#pragma unroll
        for (int j = 0; j < 16; ++j)
            acc[j] = fmaf(hs, obs_w2[h * 16 + j], acc[j]);
    }

    // ---- rho: 16 -> 64 -> 2 ----
    float r0 = rho_b2[0], r1 = rho_b2[1];
#pragma unroll 2
    for (int h = 0; h < 64; ++h) {
        float t = rho_b1[h];
#pragma unroll
        for (int j = 0; j < 16; ++j)
            t = fmaf(acc[j], rho_w1[j * 64 + h], t);
        t = relu(t);
        r0 = fmaf(t, rho_w2[2 * h],     r0);
        r1 = fmaf(t, rho_w2[2 * h + 1], r1);
    }

    // ---- psi: [rho0, rho1, g0, g1] -> 64 -> 2 ----
    float e0 = psi_b2[0], e1 = psi_b2[1];
#pragma unroll 2
    for (int h = 0; h < 64; ++h) {
        float t = fmaf(r0, psi_w1[h],
                  fmaf(r1, psi_w1[64 + h],
                  fmaf(g0, psi_w1[128 + h],
                  fmaf(g1, psi_w1[192 + h], psi_b1[h]))));
        t = relu(t);
        e0 = fmaf(t, psi_w2[2 * h],     e0);
        e1 = fmaf(t, psi_w2[2 * h + 1], e1);
    }

    // empty = tanh(e); action = tanh(empty + barrier); out = 2*action
    float a0 = tanhf(tanhf(e0) + bar0);
    float a1 = tanhf(tanhf(e1) + bar1);
    out[s] = make_float2(2.f * a0, 2.f * a1);
}

extern "C" void kernel_launch(void* const* d_in, const int* in_sizes, int n_in,
                              void* d_out, int out_size, void* d_ws, size_t ws_size,
                              hipStream_t stream) {
    dim3 grid((BATCH + 255) / 256), block(256);
    barrier_net<<<grid, block, 0, stream>>>(
        (const float*)d_in[0],
        (const float*)d_in[1],  (const float*)d_in[2],  (const float*)d_in[3],  (const float*)d_in[4],
        (const float*)d_in[5],  (const float*)d_in[6],  (const float*)d_in[7],  (const float*)d_in[8],
        (const float*)d_in[9],  (const float*)d_in[10], (const float*)d_in[11], (const float*)d_in[12],
        (const float*)d_in[13], (const float*)d_in[14], (const float*)d_in[15], (const float*)d_in[16],
        (float2*)d_out);
}